// Round 7
// baseline (830.862 us; speedup 1.0000x reference)
//
#include <hip/hip_runtime.h>

#define NN 50000
#define NE 800000
#define NL 200000
#define FEAT 128
#define HID 32
#define HEADS 8
#define H1 256   // HEADS*HID
#define CAP 64   // per-node CSR bucket capacity (P(deg>64) ~ 1e-20 for Poisson(16))

using u32 = unsigned int;

// bf16-pair helpers: u32 holds [lo16 = col even, hi16 = col odd]
__device__ __forceinline__ float bflo(u32 v) { return __uint_as_float(v << 16); }
__device__ __forceinline__ float bfhi(u32 v) { return __uint_as_float(v & 0xffff0000u); }
__device__ __forceinline__ u32 packbf(float a, float b) {
  u32 ua = __float_as_uint(a), ub = __float_as_uint(b);
  ua += 0x7fffu + ((ua >> 16) & 1u);   // RNE
  ub += 0x7fffu + ((ub >> 16) & 1u);
  return (ua >> 16) | (ub & 0xffff0000u);
}

// ---------------------------------------------------------------------------
// v-vector precompute (collapses dst-side [N,256] GEMMs into matvecs)
// ---------------------------------------------------------------------------
__global__ __launch_bounds__(256) void k_vprep(
    const float* __restrict__ w1s, const float* __restrict__ w1d,
    const float* __restrict__ a1s, const float* __restrict__ a1d,
    const float* __restrict__ w2s, const float* __restrict__ w2d,
    const float* __restrict__ a2s, const float* __restrict__ a2d,
    float* __restrict__ v1s, float* __restrict__ v1d,
    float* __restrict__ v2s, float* __restrict__ v2d) {
  int tid = threadIdx.x;
  int k = tid >> 3, h = tid & 7;
  float ss = 0.f, sd = 0.f;
  for (int c = 0; c < 32; ++c) {
    ss += w1s[k * H1 + h * 32 + c] * a1s[h * 32 + c];
    sd += w1d[k * H1 + h * 32 + c] * a1d[h * 32 + c];
  }
  v1s[k * 8 + h] = ss;
  v1d[k * 8 + h] = sd;
  float s2 = 0.f, d2 = 0.f;
  for (int c = 0; c < 32; ++c) {
    s2 += w2s[tid * 32 + c] * a2s[c];
    d2 += w2d[tid * 32 + c] * a2d[c];
  }
  v2s[tid] = s2;
  v2d[tid] = d2;
}

// ---------------------------------------------------------------------------
// Bucketed CSR fill (slot order irrelevant for sums)
// ---------------------------------------------------------------------------
__global__ void k_fill(const int* __restrict__ src, const int* __restrict__ dst,
                       int* __restrict__ cnt, int* __restrict__ csr) {
  int e = blockIdx.x * 256 + threadIdx.x;
  if (e >= NE) return;
  int d = dst[e];
  int slot = atomicAdd(&cnt[d], 1);
  if (slot < CAP) csr[(size_t)d * CAP + slot] = src[e];
}

// ---------------------------------------------------------------------------
// Layer-1 prep: h0 = x@lin_w+lin_b (LDS), write h0b (bf16, 3.2MB) + as1/ad1.
// xs1 is NO LONGER materialized (projection moved after aggregation).
// ---------------------------------------------------------------------------
__global__ __launch_bounds__(256) void k_l1(
    const float* __restrict__ x, const float* __restrict__ lin_w,
    const float* __restrict__ lin_b, const float* __restrict__ v1s,
    const float* __restrict__ v1d, u32* __restrict__ h0b,
    float* __restrict__ as1, float* __restrict__ ad1) {
  __shared__ float wl[FEAT * HID];   // 16KB
  __shared__ float xl[32 * FEAT];    // 16KB
  __shared__ float h0l[32 * HID];    // 4KB
  __shared__ float vsl[HID * 8], vdl[HID * 8], bl[HID];
  int tid = threadIdx.x;
  for (int i = tid; i < (FEAT * HID) / 4; i += 256)
    ((float4*)wl)[i] = ((const float4*)lin_w)[i];
  vsl[tid] = v1s[tid];
  vdl[tid] = v1d[tid];
  if (tid < HID) bl[tid] = lin_b[tid];
  int n0 = blockIdx.x * 32;
  for (int i = tid; i < (32 * FEAT) / 4; i += 256) {
    int n = n0 + (i >> 5);
    ((float4*)xl)[i] = (n < NN) ? ((const float4*)x)[(size_t)n * 32 + (i & 31)]
                                : make_float4(0.f, 0.f, 0.f, 0.f);
  }
  __syncthreads();
  {  // h0 tile into LDS
    int nl = tid >> 5, c = tid & 31;
    float acc[4] = {0.f, 0.f, 0.f, 0.f};
    for (int k = 0; k < FEAT; ++k) {
      float wv = wl[k * HID + c];
#pragma unroll
      for (int j = 0; j < 4; ++j) acc[j] += xl[(nl + 8 * j) * FEAT + k] * wv;
    }
#pragma unroll
    for (int j = 0; j < 4; ++j) h0l[(nl + 8 * j) * HID + c] = acc[j] + bl[c];
  }
  __syncthreads();
  // h0b bf16 write: 32 nodes x 16 u32
  for (int i = tid; i < 512; i += 256) {
    int nl = i >> 4, cp = i & 15;
    int n = n0 + nl;
    if (n < NN)
      h0b[(size_t)n * 16 + cp] =
          packbf(h0l[nl * 32 + 2 * cp], h0l[nl * 32 + 2 * cp + 1]);
  }
  {  // as1/ad1: thread (node = tid>>3, head = tid&7)
    int nl = tid >> 3, h = tid & 7;
    int n = n0 + nl;
    if (n < NN) {
      float ss = 0.f, sd = 0.f;
#pragma unroll
      for (int k = 0; k < HID; ++k) {
        float hv = h0l[nl * HID + k];
        ss += hv * vsl[k * 8 + h];
        sd += hv * vdl[k * 8 + h];
      }
      as1[(size_t)n * 8 + h] = ss;
      ad1[(size_t)n * 8 + h] = sd;
    }
  }
}

// ---------------------------------------------------------------------------
// FUSED conv1-aggregate + both layer projections. Wave per node, 16 nodes per
// 256-thread block (50000 = 3125*16, no tail).
//  Phase E : agg[h][c] = sum_j e_jh * h0[s_j][c]  (h0-space, 64B/edge gather,
//            h0b 3.2MB -> per-XCD-L2-resident), den[h] = sum_j e_jh.
//  Phase P1: h1[h*32+co] = relu(agg[h]@W1s_h / den[h] + b1)  (h1 stays in LDS)
//  Phase P2: xs2 = h1@w2s (bf16 out), as2/ad2 = h1.v2s/v2d.
// Lane layout: c = lane&31 (column), hq = lane>>5; lane owns heads hq*4..+3.
// ---------------------------------------------------------------------------
__global__ __launch_bounds__(256) void k_aggf(
    const int* __restrict__ cnt, const int* __restrict__ csr,
    const u32* __restrict__ h0b, const float* __restrict__ as1,
    const float* __restrict__ ad1, const float* __restrict__ w1s,
    const float* __restrict__ b1, const float* __restrict__ w2s,
    const float* __restrict__ v2s, const float* __restrict__ v2d,
    u32* __restrict__ xs2b, float* __restrict__ as2, float* __restrict__ ad2) {
  __shared__ float w1sl[HID * H1];    // 32KB, [k*256 + co]
  __shared__ float w2sl[H1 * HID];    // 32KB, [k*32 + c]
  __shared__ float v2sl[H1], v2dl[H1], b1l[H1];
  __shared__ float sacc[4][8 * 33];   // per-wave agg, stride-33 pad
  __shared__ float sden[4][8];
  __shared__ float sh1[4][H1];        // per-wave h1
  int tid = threadIdx.x;
  for (int i = tid; i < 2048; i += 256) {
    ((float4*)w1sl)[i] = ((const float4*)w1s)[i];
    ((float4*)w2sl)[i] = ((const float4*)w2s)[i];
  }
  v2sl[tid] = v2s[tid];
  v2dl[tid] = v2d[tid];
  b1l[tid] = b1[tid];
  __syncthreads();
  int w = tid >> 6, lane = tid & 63;
  int c = lane & 31, hq = lane >> 5, hb = hq * 4;
  for (int t = 0; t < 4; ++t) {
    int n = blockIdx.x * 16 + t * 4 + w;
    // ---- Phase E: edge aggregation in h0-space ----
    float adreg = (lane < 8) ? ad1[(size_t)n * 8 + lane] : 0.f;
    float acc0 = 0.f, acc1 = 0.f, acc2 = 0.f, acc3 = 0.f, den = 0.f;
    int m = min(cnt[n], CAP);
    const int* cs = csr + (size_t)n * CAP;
    int j = 0;
    for (; j + 1 < m; j += 2) {
      int sA = cs[j], sB = cs[j + 1];
      u32 wA = h0b[(size_t)sA * 16 + (c >> 1)];
      u32 wB = h0b[(size_t)sB * 16 + (c >> 1)];
      float eA = 0.f, eB = 0.f;
      if (lane < 8) {
        float aA = as1[(size_t)sA * 8 + lane] + adreg;
        aA = aA > 0.f ? aA : 0.2f * aA;
        float aB = as1[(size_t)sB * 8 + lane] + adreg;
        aB = aB > 0.f ? aB : 0.2f * aB;
        eA = __expf(aA);
        eB = __expf(aB);
        den += eA + eB;
      }
      float hA = (c & 1) ? bfhi(wA) : bflo(wA);
      float hB = (c & 1) ? bfhi(wB) : bflo(wB);
      acc0 += __shfl(eA, hb + 0) * hA + __shfl(eB, hb + 0) * hB;
      acc1 += __shfl(eA, hb + 1) * hA + __shfl(eB, hb + 1) * hB;
      acc2 += __shfl(eA, hb + 2) * hA + __shfl(eB, hb + 2) * hB;
      acc3 += __shfl(eA, hb + 3) * hA + __shfl(eB, hb + 3) * hB;
    }
    if (j < m) {
      int sA = cs[j];
      u32 wA = h0b[(size_t)sA * 16 + (c >> 1)];
      float eA = 0.f;
      if (lane < 8) {
        float aA = as1[(size_t)sA * 8 + lane] + adreg;
        aA = aA > 0.f ? aA : 0.2f * aA;
        eA = __expf(aA);
        den += eA;
      }
      float hA = (c & 1) ? bfhi(wA) : bflo(wA);
      acc0 += __shfl(eA, hb + 0) * hA;
      acc1 += __shfl(eA, hb + 1) * hA;
      acc2 += __shfl(eA, hb + 2) * hA;
      acc3 += __shfl(eA, hb + 3) * hA;
    }
    sacc[w][(hb + 0) * 33 + c] = acc0;
    sacc[w][(hb + 1) * 33 + c] = acc1;
    sacc[w][(hb + 2) * 33 + c] = acc2;
    sacc[w][(hb + 3) * 33 + c] = acc3;
    if (lane < 8) sden[w][lane] = den;
    __syncthreads();
    // ---- Phase P1: per-head projection agg@W1s_h -> h1 (LDS) ----
    float o0 = 0.f, o1 = 0.f, o2 = 0.f, o3 = 0.f;
#pragma unroll
    for (int k = 0; k < 32; ++k) {
      float a0 = sacc[w][(hb + 0) * 33 + k];
      float a1 = sacc[w][(hb + 1) * 33 + k];
      float a2 = sacc[w][(hb + 2) * 33 + k];
      float a3 = sacc[w][(hb + 3) * 33 + k];
      o0 += a0 * w1sl[k * H1 + (hb + 0) * 32 + c];
      o1 += a1 * w1sl[k * H1 + (hb + 1) * 32 + c];
      o2 += a2 * w1sl[k * H1 + (hb + 2) * 32 + c];
      o3 += a3 * w1sl[k * H1 + (hb + 3) * 32 + c];
    }
    {
      float i0 = 1.f / (sden[w][hb + 0] + 1e-16f);
      float i1 = 1.f / (sden[w][hb + 1] + 1e-16f);
      float i2 = 1.f / (sden[w][hb + 2] + 1e-16f);
      float i3 = 1.f / (sden[w][hb + 3] + 1e-16f);
      float r0 = o0 * i0 + b1l[(hb + 0) * 32 + c];
      float r1 = o1 * i1 + b1l[(hb + 1) * 32 + c];
      float r2 = o2 * i2 + b1l[(hb + 2) * 32 + c];
      float r3 = o3 * i3 + b1l[(hb + 3) * 32 + c];
      sh1[w][(hb + 0) * 32 + c] = r0 > 0.f ? r0 : 0.f;
      sh1[w][(hb + 1) * 32 + c] = r1 > 0.f ? r1 : 0.f;
      sh1[w][(hb + 2) * 32 + c] = r2 > 0.f ? r2 : 0.f;
      sh1[w][(hb + 3) * 32 + c] = r3 > 0.f ? r3 : 0.f;
    }
    __syncthreads();
    // ---- Phase P2: xs2 = h1@w2s (bf16), as2/ad2 = h1.v2s/v2d ----
    float p = 0.f;
    int k0 = hq * 128;
#pragma unroll
    for (int k = 0; k < 128; ++k)
      p += sh1[w][k0 + k] * w2sl[(k0 + k) * HID + c];
    p += __shfl_xor(p, 32);
    float other = __shfl_xor(p, 1);
    if (hq == 0 && (c & 1) == 0)
      xs2b[(size_t)n * 16 + (c >> 1)] = packbf(p, other);
    float ss = 0.f, sd = 0.f;
#pragma unroll
    for (int i2 = 0; i2 < 4; ++i2) {
      float hv = sh1[w][lane + 64 * i2];
      ss += hv * v2sl[lane + 64 * i2];
      sd += hv * v2dl[lane + 64 * i2];
    }
#pragma unroll
    for (int mk = 32; mk >= 1; mk >>= 1) {
      ss += __shfl_xor(ss, mk);
      sd += __shfl_xor(sd, mk);
    }
    if (lane == 0) {
      as2[n] = ss;
      ad2[n] = sd;
    }
    __syncthreads();
  }
}

// ---------------------------------------------------------------------------
// conv2 aggregate: 8 nodes/block; 2 edge groups x 16 lanes x bf16-pair.
// xs2b 3.2MB -> L2-resident gather. h2 fp32 (precision anchor).
// ---------------------------------------------------------------------------
__global__ __launch_bounds__(256) void k_agg2(
    const int* __restrict__ cnt, const int* __restrict__ csr,
    const u32* __restrict__ xs2b, const float* __restrict__ as2,
    const float* __restrict__ ad2, const float* __restrict__ b2,
    float* __restrict__ h2) {
  int tid = threadIdx.x;
  int n = blockIdx.x * 8 + (tid >> 5);
  int sub = tid & 31, g = sub >> 4, l = sub & 15;
  if (n >= NN) return;
  float adn = ad2[n];
  int m = min(cnt[n], CAP);
  const int* cs = csr + (size_t)n * CAP;
  float a0 = 0.f, a1v = 0.f, ea = 0.f;
  int j = g;
  for (; j + 2 < m; j += 4) {
    int sA = cs[j], sB = cs[j + 2];
    float alA = as2[sA] + adn; alA = alA > 0.f ? alA : 0.2f * alA;
    float alB = as2[sB] + adn; alB = alB > 0.f ? alB : 0.2f * alB;
    float eA = __expf(alA), eB = __expf(alB);
    u32 vA = xs2b[(size_t)sA * 16 + l], vB = xs2b[(size_t)sB * 16 + l];
    a0 += bflo(vA) * eA + bflo(vB) * eB;
    a1v += bfhi(vA) * eA + bfhi(vB) * eB;
    ea += eA + eB;
  }
  for (; j < m; j += 2) {
    int s = cs[j];
    float al = as2[s] + adn; al = al > 0.f ? al : 0.2f * al;
    float ee = __expf(al);
    u32 v = xs2b[(size_t)s * 16 + l];
    a0 += bflo(v) * ee;
    a1v += bfhi(v) * ee;
    ea += ee;
  }
  a0 += __shfl_xor(a0, 16);
  a1v += __shfl_xor(a1v, 16);
  ea += __shfl_xor(ea, 16);
  if (g == 0) {
    float inv = 1.f / (ea + 1e-16f);
    float o0 = a0 * inv + b2[2 * l];
    float o1 = a1v * inv + b2[2 * l + 1];
    ((float2*)h2)[(size_t)n * 16 + l] = make_float2(o0, o1);
  }
}

// ---------------------------------------------------------------------------
// classifier: 8 lanes per label, float4 loads, shfl reduce
// ---------------------------------------------------------------------------
__global__ __launch_bounds__(256) void k_pred(const int* __restrict__ eli,
                                              const float* __restrict__ h2,
                                              float* __restrict__ out) {
  int gid = blockIdx.x * 256 + threadIdx.x;
  int lab = gid >> 3, q = gid & 7;
  if (lab >= NL) return;
  int a = eli[lab], b = eli[NL + lab];
  float4 va = ((const float4*)(h2 + (size_t)a * HID))[q];
  float4 vb = ((const float4*)(h2 + (size_t)b * HID))[q];
  float s = va.x * vb.x + va.y * vb.y + va.z * vb.z + va.w * vb.w;
  s += __shfl_xor(s, 1);
  s += __shfl_xor(s, 2);
  s += __shfl_xor(s, 4);
  if (q == 0) out[lab] = s;
}

extern "C" void kernel_launch(void* const* d_in, const int* in_sizes, int n_in,
                              void* d_out, int out_size, void* d_ws, size_t ws_size,
                              hipStream_t stream) {
  const float* x     = (const float*)d_in[0];
  const int*   ei    = (const int*)d_in[1];
  const int*   eli   = (const int*)d_in[2];
  const float* lin_w = (const float*)d_in[3];
  const float* lin_b = (const float*)d_in[4];
  const float* w1s   = (const float*)d_in[5];
  const float* w1d   = (const float*)d_in[6];
  const float* a1s   = (const float*)d_in[7];
  const float* a1d   = (const float*)d_in[8];
  const float* b1    = (const float*)d_in[9];
  const float* w2s   = (const float*)d_in[10];
  const float* w2d   = (const float*)d_in[11];
  const float* a2s   = (const float*)d_in[12];
  const float* a2d   = (const float*)d_in[13];
  const float* b2    = (const float*)d_in[14];
  float* out = (float*)d_out;

  char* p = (char*)d_ws;
  auto take = [&](size_t bytes) {
    char* r = p;
    p += (bytes + 255) & ~(size_t)255;
    return r;
  };
  int*   cnt  = (int*)take((size_t)NN * 4);           // zeroed per call
  int*   csr  = (int*)take((size_t)NN * CAP * 4);     // 12.8MB
  u32*   h0b  = (u32*)take((size_t)NN * 16 * 4);      // 3.2MB (bf16 pairs)
  float* as1  = (float*)take((size_t)NN * 8 * 4);
  float* ad1  = (float*)take((size_t)NN * 8 * 4);
  u32*   xs2b = (u32*)take((size_t)NN * 16 * 4);      // 3.2MB
  float* as2  = (float*)take((size_t)NN * 4);
  float* ad2  = (float*)take((size_t)NN * 4);
  float* h2   = (float*)take((size_t)NN * HID * 4);   // fp32
  float* v1s  = (float*)take(256 * 4);
  float* v1d  = (float*)take(256 * 4);
  float* v2s  = (float*)take(256 * 4);
  float* v2d  = (float*)take(256 * 4);

  const int* esrc = ei;
  const int* edst = ei + NE;

  hipMemsetAsync(cnt, 0, (size_t)NN * 4, stream);
  k_vprep<<<1, 256, 0, stream>>>(w1s, w1d, a1s, a1d, w2s, w2d, a2s, a2d,
                                 v1s, v1d, v2s, v2d);
  k_fill<<<(NE + 255) / 256, 256, 0, stream>>>(esrc, edst, cnt, csr);
  k_l1<<<(NN + 31) / 32, 256, 0, stream>>>(x, lin_w, lin_b, v1s, v1d,
                                           h0b, as1, ad1);
  k_aggf<<<NN / 16, 256, 0, stream>>>(cnt, csr, h0b, as1, ad1, w1s, b1, w2s,
                                      v2s, v2d, xs2b, as2, ad2);
  k_agg2<<<(NN + 7) / 8, 256, 0, stream>>>(cnt, csr, xs2b, as2, ad2, b2, h2);
  k_pred<<<(NL * 8 + 255) / 256, 256, 0, stream>>>(eli, h2, out);
}

// Round 8
// 300.332 us; speedup vs baseline: 2.7665x; 2.7665x over previous
//
#include <hip/hip_runtime.h>

#define NN 50000
#define NE 800000
#define NL 200000
#define FEAT 128
#define HID 32
#define HEADS 8
#define H1 256   // HEADS*HID
#define CAP 64   // per-node CSR bucket capacity (P(deg>64) ~ 1e-20 for Poisson(16))
#define NB 32    // nodes per block in k_p12

using u32 = unsigned int;

__device__ __forceinline__ float bflo(u32 v) { return __uint_as_float(v << 16); }
__device__ __forceinline__ float bfhi(u32 v) { return __uint_as_float(v & 0xffff0000u); }
__device__ __forceinline__ u32 packbf(float a, float b) {
  u32 ua = __float_as_uint(a), ub = __float_as_uint(b);
  ua += 0x7fffu + ((ua >> 16) & 1u);   // RNE
  ub += 0x7fffu + ((ub >> 16) & 1u);
  return (ua >> 16) | (ub & 0xffff0000u);
}

// ---------------------------------------------------------------------------
// v-vector precompute (collapses dst-side [N,256] GEMMs into matvecs)
// ---------------------------------------------------------------------------
__global__ __launch_bounds__(256) void k_vprep(
    const float* __restrict__ w1s, const float* __restrict__ w1d,
    const float* __restrict__ a1s, const float* __restrict__ a1d,
    const float* __restrict__ w2s, const float* __restrict__ w2d,
    const float* __restrict__ a2s, const float* __restrict__ a2d,
    float* __restrict__ v1s, float* __restrict__ v1d,
    float* __restrict__ v2s, float* __restrict__ v2d) {
  int tid = threadIdx.x;
  int k = tid >> 3, h = tid & 7;
  float ss = 0.f, sd = 0.f;
  for (int c = 0; c < 32; ++c) {
    ss += w1s[k * H1 + h * 32 + c] * a1s[h * 32 + c];
    sd += w1d[k * H1 + h * 32 + c] * a1d[h * 32 + c];
  }
  v1s[k * 8 + h] = ss;
  v1d[k * 8 + h] = sd;
  float s2 = 0.f, d2 = 0.f;
  for (int c = 0; c < 32; ++c) {
    s2 += w2s[tid * 32 + c] * a2s[c];
    d2 += w2d[tid * 32 + c] * a2d[c];
  }
  v2s[tid] = s2;
  v2d[tid] = d2;
}

// ---------------------------------------------------------------------------
// Bucketed CSR fill
// ---------------------------------------------------------------------------
__global__ void k_fill(const int* __restrict__ src, const int* __restrict__ dst,
                       int* __restrict__ cnt, int* __restrict__ csr) {
  int e = blockIdx.x * 256 + threadIdx.x;
  if (e >= NE) return;
  int d = dst[e];
  int slot = atomicAdd(&cnt[d], 1);
  if (slot < CAP) csr[(size_t)d * CAP + slot] = src[e];
}

// ---------------------------------------------------------------------------
// Layer-1 prep: h0 = x@lin_w+lin_b (LDS), write h0b (bf16, 3.2MB) + as1/ad1.
// ---------------------------------------------------------------------------
__global__ __launch_bounds__(256) void k_l1(
    const float* __restrict__ x, const float* __restrict__ lin_w,
    const float* __restrict__ lin_b, const float* __restrict__ v1s,
    const float* __restrict__ v1d, u32* __restrict__ h0b,
    float* __restrict__ as1, float* __restrict__ ad1) {
  __shared__ float wl[FEAT * HID];   // 16KB
  __shared__ float xl[32 * FEAT];    // 16KB
  __shared__ float h0l[32 * HID];    // 4KB
  __shared__ float vsl[HID * 8], vdl[HID * 8], bl[HID];
  int tid = threadIdx.x;
  for (int i = tid; i < (FEAT * HID) / 4; i += 256)
    ((float4*)wl)[i] = ((const float4*)lin_w)[i];
  vsl[tid] = v1s[tid];
  vdl[tid] = v1d[tid];
  if (tid < HID) bl[tid] = lin_b[tid];
  int n0 = blockIdx.x * 32;
  for (int i = tid; i < (32 * FEAT) / 4; i += 256) {
    int n = n0 + (i >> 5);
    ((float4*)xl)[i] = (n < NN) ? ((const float4*)x)[(size_t)n * 32 + (i & 31)]
                                : make_float4(0.f, 0.f, 0.f, 0.f);
  }
  __syncthreads();
  {
    int nl = tid >> 5, c = tid & 31;
    float acc[4] = {0.f, 0.f, 0.f, 0.f};
    for (int k = 0; k < FEAT; ++k) {
      float wv = wl[k * HID + c];
#pragma unroll
      for (int j = 0; j < 4; ++j) acc[j] += xl[(nl + 8 * j) * FEAT + k] * wv;
    }
#pragma unroll
    for (int j = 0; j < 4; ++j) h0l[(nl + 8 * j) * HID + c] = acc[j] + bl[c];
  }
  __syncthreads();
  for (int i = tid; i < 512; i += 256) {
    int nl = i >> 4, cp = i & 15;
    int n = n0 + nl;
    if (n < NN)
      h0b[(size_t)n * 16 + cp] =
          packbf(h0l[nl * 32 + 2 * cp], h0l[nl * 32 + 2 * cp + 1]);
  }
  {
    int nl = tid >> 3, h = tid & 7;
    int n = n0 + nl;
    if (n < NN) {
      float ss = 0.f, sd = 0.f;
#pragma unroll
      for (int k = 0; k < HID; ++k) {
        float hv = h0l[nl * HID + k];
        ss += hv * vsl[k * 8 + h];
        sd += hv * vdl[k * 8 + h];
      }
      as1[(size_t)n * 8 + h] = ss;
      ad1[(size_t)n * 8 + h] = sd;
    }
  }
}

// ---------------------------------------------------------------------------
// Edge aggregation in h0-space. WAVE PER NODE, no LDS, no barriers.
// Half-wave 0 (lanes 0-31) processes even edges, half-wave 1 odd edges.
// Lane c = lane&31 owns h0 column c; all 8 head-accumulators in registers.
// e_jh computed by lanes (lane&31)<8 of each half; broadcast via __shfl.
// Cross-half combine at the end via shfl_xor(32).
// agg (bf16) + den written per node; consumed by k_p12.
// ---------------------------------------------------------------------------
__global__ __launch_bounds__(256) void k_aggE(
    const int* __restrict__ cnt, const int* __restrict__ csr,
    const u32* __restrict__ h0b, const float* __restrict__ as1,
    const float* __restrict__ ad1, u32* __restrict__ aggb,
    float* __restrict__ den1) {
  int tid = threadIdx.x;
  int w = tid >> 6, lane = tid & 63;
  int half = lane >> 5, c = lane & 31;
  int n = blockIdx.x * 4 + w;          // grid = NN/4 exactly
  int hh = c;                           // head id if < 8
  bool ise = hh < 8;
  float adreg = ise ? ad1[(size_t)n * 8 + hh] : 0.f;
  float acc[8] = {0.f, 0.f, 0.f, 0.f, 0.f, 0.f, 0.f, 0.f};
  float den = 0.f;
  int m = min(cnt[n], CAP);
  const int* cs = csr + (size_t)n * CAP;
  int sb = lane & 32;                   // shfl source base for own half
  int cp = c >> 1;
  int j = 0;
  // 2-deep pipeline: 4 edges in flight (2 per half)
  for (; j + 3 < m; j += 4) {
    int s0 = cs[j + half];
    int s1 = cs[j + 2 + half];
    u32 w0 = h0b[(size_t)s0 * 16 + cp];
    u32 w1 = h0b[(size_t)s1 * 16 + cp];
    float e0 = 0.f, e1 = 0.f;
    if (ise) {
      float a0 = as1[(size_t)s0 * 8 + hh] + adreg;
      a0 = a0 > 0.f ? a0 : 0.2f * a0;
      float a1 = as1[(size_t)s1 * 8 + hh] + adreg;
      a1 = a1 > 0.f ? a1 : 0.2f * a1;
      e0 = __expf(a0);
      e1 = __expf(a1);
      den += e0 + e1;
    }
    float h0v = (c & 1) ? bfhi(w0) : bflo(w0);
    float h1v = (c & 1) ? bfhi(w1) : bflo(w1);
#pragma unroll
    for (int h = 0; h < 8; ++h)
      acc[h] += __shfl(e0, sb + h) * h0v + __shfl(e1, sb + h) * h1v;
  }
  for (; j < m; j += 2) {
    int idx = j + half;
    int sA = cs[idx < m ? idx : m - 1];
    u32 wv = h0b[(size_t)sA * 16 + cp];
    float e = 0.f;
    if (ise && idx < m) {
      float a = as1[(size_t)sA * 8 + hh] + adreg;
      a = a > 0.f ? a : 0.2f * a;
      e = __expf(a);
      den += e;
    }
    float hv = (c & 1) ? bfhi(wv) : bflo(wv);
#pragma unroll
    for (int h = 0; h < 8; ++h) acc[h] += __shfl(e, sb + h) * hv;
  }
  // combine halves
#pragma unroll
  for (int h = 0; h < 8; ++h) acc[h] += __shfl_xor(acc[h], 32);
  den += __shfl_xor(den, 32);
  if (lane < 8) den1[(size_t)n * 8 + lane] = den;
  // pack bf16 pairs, lanes<32 even write
#pragma unroll
  for (int h = 0; h < 8; ++h) {
    float other = __shfl_xor(acc[h], 1);
    if (lane < 32 && !(lane & 1))
      aggb[(size_t)n * 128 + h * 16 + cp] = packbf(acc[h], other);
  }
}

// ---------------------------------------------------------------------------
// P1+P2: per node, h1 = relu(agg@W1s/den + b1) (per-head 32x32), then
// xs2 = h1@w2s (bf16), as2/ad2 = h1.v2s/v2d. Weights held in REGISTERS
// (thread (h,c) owns a W1s column; thread (g,c) owns a W2s column);
// agg staged bf16 in LDS (broadcast reads). 32 nodes/block, 4 barriers.
// ---------------------------------------------------------------------------
__global__ __launch_bounds__(256) void k_p12(
    const u32* __restrict__ aggb, const float* __restrict__ den1,
    const float* __restrict__ w1s, const float* __restrict__ b1,
    const float* __restrict__ w2s, const float* __restrict__ v2s,
    const float* __restrict__ v2d, u32* __restrict__ xs2b,
    float* __restrict__ as2, float* __restrict__ ad2) {
  __shared__ u32 aggl[NB * 128];      // 16KB; reused as part[] after P1
  __shared__ float sh1[NB * 257];     // 32.9KB (pad 257 for v2-dot phase)
  __shared__ float denl[NB * 8];
  __shared__ float v2sl[H1], v2dl[H1];
  int tid = threadIdx.x;
  int n0 = blockIdx.x * NB;
  int h = tid >> 5, c = tid & 31;     // (h,c) for P1; (g,c2)=(h,c) for P2
  float w1reg[32], w2reg[32];
#pragma unroll
  for (int k = 0; k < 32; ++k) w1reg[k] = w1s[k * H1 + tid];
#pragma unroll
  for (int k = 0; k < 32; ++k) w2reg[k] = w2s[h * 1024 + k * 32 + c];
  float b1reg = b1[tid];
  v2sl[tid] = v2s[tid];
  v2dl[tid] = v2d[tid];
  // stage agg (bf16) + den
  for (int q = 0; q < 4; ++q) {
    int i = tid + 256 * q;            // uint4 index; node = i>>5
    int nn = n0 + (i >> 5);
    ((uint4*)aggl)[i] = (nn < NN) ? ((const uint4*)aggb)[(size_t)n0 * 32 + i]
                                  : make_uint4(0u, 0u, 0u, 0u);
  }
  {
    int nn = n0 + (tid >> 3);
    denl[tid] = (nn < NN) ? den1[(size_t)nn * 8 + (tid & 7)] : 1.f;
  }
  __syncthreads();
  // P1: sh1[n][h*32+c] = relu(sum_k agg[n][h][k]*W1s[k][h*32+c] * inv + b1)
  for (int n = 0; n < NB; ++n) {
    float out = 0.f;
#pragma unroll
    for (int kp = 0; kp < 16; ++kp) {
      u32 v = aggl[n * 128 + h * 16 + kp];
      out += bflo(v) * w1reg[2 * kp] + bfhi(v) * w1reg[2 * kp + 1];
    }
    float inv = 1.f / (denl[n * 8 + h] + 1e-16f);
    float r = out * inv + b1reg;
    sh1[n * 257 + tid] = r > 0.f ? r : 0.f;
  }
  __syncthreads();
  // P2: partial xs2 per wave (k in [w*64,(w+1)*64)), write to part[]
  float* part = (float*)aggl;         // [4][NB][32]
  int wv = tid >> 6, lane = tid & 63;
  for (int n = 0; n < NB; ++n) {
    float pp = 0.f;
#pragma unroll
    for (int k = 0; k < 32; ++k)
      pp += sh1[n * 257 + h * 32 + k] * w2reg[k];
    pp += __shfl_xor(pp, 32);
    if (lane < 32) part[wv * (NB * 32) + n * 32 + c] = pp;
  }
  __syncthreads();
  // combine xs2 partials -> bf16 write
#pragma unroll
  for (int q = 0; q < 4; ++q) {
    int slot = tid + 256 * q;         // = n*32 + cc
    int nn = slot >> 5, cc = slot & 31;
    float s = part[slot] + part[1024 + slot] + part[2048 + slot] +
              part[3072 + slot];
    float other = __shfl_xor(s, 1);
    int gn = n0 + nn;
    if (gn < NN && !(cc & 1))
      xs2b[(size_t)gn * 16 + (cc >> 1)] = packbf(s, other);
  }
  // v2 dots: thread (nn = tid>>3, kg = tid&7), bank-rotated reads
  {
    int nn = tid >> 3, kg = tid & 7;
    float ssum = 0.f, dsum = 0.f;
#pragma unroll
    for (int k = 0; k < 32; ++k) {
      int ki = kg * 32 + ((k + 4 * kg) & 31);
      float hv = sh1[nn * 257 + ki];
      ssum += hv * v2sl[ki];
      dsum += hv * v2dl[ki];
    }
    ssum += __shfl_xor(ssum, 1);
    dsum += __shfl_xor(dsum, 1);
    ssum += __shfl_xor(ssum, 2);
    dsum += __shfl_xor(dsum, 2);
    ssum += __shfl_xor(ssum, 4);
    dsum += __shfl_xor(dsum, 4);
    int gn = n0 + nn;
    if (kg == 0 && gn < NN) {
      as2[gn] = ssum;
      ad2[gn] = dsum;
    }
  }
}

// ---------------------------------------------------------------------------
// conv2 aggregate: 8 nodes/block; xs2b 3.2MB L2-resident gather. h2 fp32.
// ---------------------------------------------------------------------------
__global__ __launch_bounds__(256) void k_agg2(
    const int* __restrict__ cnt, const int* __restrict__ csr,
    const u32* __restrict__ xs2b, const float* __restrict__ as2,
    const float* __restrict__ ad2, const float* __restrict__ b2,
    float* __restrict__ h2) {
  int tid = threadIdx.x;
  int n = blockIdx.x * 8 + (tid >> 5);
  int sub = tid & 31, g = sub >> 4, l = sub & 15;
  if (n >= NN) return;
  float adn = ad2[n];
  int m = min(cnt[n], CAP);
  const int* cs = csr + (size_t)n * CAP;
  float a0 = 0.f, a1v = 0.f, ea = 0.f;
  int j = g;
  for (; j + 2 < m; j += 4) {
    int sA = cs[j], sB = cs[j + 2];
    float alA = as2[sA] + adn; alA = alA > 0.f ? alA : 0.2f * alA;
    float alB = as2[sB] + adn; alB = alB > 0.f ? alB : 0.2f * alB;
    float eA = __expf(alA), eB = __expf(alB);
    u32 vA = xs2b[(size_t)sA * 16 + l], vB = xs2b[(size_t)sB * 16 + l];
    a0 += bflo(vA) * eA + bflo(vB) * eB;
    a1v += bfhi(vA) * eA + bfhi(vB) * eB;
    ea += eA + eB;
  }
  for (; j < m; j += 2) {
    int s = cs[j];
    float al = as2[s] + adn; al = al > 0.f ? al : 0.2f * al;
    float ee = __expf(al);
    u32 v = xs2b[(size_t)s * 16 + l];
    a0 += bflo(v) * ee;
    a1v += bfhi(v) * ee;
    ea += ee;
  }
  a0 += __shfl_xor(a0, 16);
  a1v += __shfl_xor(a1v, 16);
  ea += __shfl_xor(ea, 16);
  if (g == 0) {
    float inv = 1.f / (ea + 1e-16f);
    float o0 = a0 * inv + b2[2 * l];
    float o1 = a1v * inv + b2[2 * l + 1];
    ((float2*)h2)[(size_t)n * 16 + l] = make_float2(o0, o1);
  }
}

// ---------------------------------------------------------------------------
// classifier: 8 lanes per label, float4 loads, shfl reduce
// ---------------------------------------------------------------------------
__global__ __launch_bounds__(256) void k_pred(const int* __restrict__ eli,
                                              const float* __restrict__ h2,
                                              float* __restrict__ out) {
  int gid = blockIdx.x * 256 + threadIdx.x;
  int lab = gid >> 3, q = gid & 7;
  if (lab >= NL) return;
  int a = eli[lab], b = eli[NL + lab];
  float4 va = ((const float4*)(h2 + (size_t)a * HID))[q];
  float4 vb = ((const float4*)(h2 + (size_t)b * HID))[q];
  float s = va.x * vb.x + va.y * vb.y + va.z * vb.z + va.w * vb.w;
  s += __shfl_xor(s, 1);
  s += __shfl_xor(s, 2);
  s += __shfl_xor(s, 4);
  if (q == 0) out[lab] = s;
}

extern "C" void kernel_launch(void* const* d_in, const int* in_sizes, int n_in,
                              void* d_out, int out_size, void* d_ws, size_t ws_size,
                              hipStream_t stream) {
  const float* x     = (const float*)d_in[0];
  const int*   ei    = (const int*)d_in[1];
  const int*   eli   = (const int*)d_in[2];
  const float* lin_w = (const float*)d_in[3];
  const float* lin_b = (const float*)d_in[4];
  const float* w1s   = (const float*)d_in[5];
  const float* w1d   = (const float*)d_in[6];
  const float* a1s   = (const float*)d_in[7];
  const float* a1d   = (const float*)d_in[8];
  const float* b1    = (const float*)d_in[9];
  const float* w2s   = (const float*)d_in[10];
  const float* w2d   = (const float*)d_in[11];
  const float* a2s   = (const float*)d_in[12];
  const float* a2d   = (const float*)d_in[13];
  const float* b2    = (const float*)d_in[14];
  float* out = (float*)d_out;

  char* p = (char*)d_ws;
  auto take = [&](size_t bytes) {
    char* r = p;
    p += (bytes + 255) & ~(size_t)255;
    return r;
  };
  int*   cnt  = (int*)take((size_t)NN * 4);           // zeroed per call
  int*   csr  = (int*)take((size_t)NN * CAP * 4);     // 12.8MB
  u32*   h0b  = (u32*)take((size_t)NN * 16 * 4);      // 3.2MB (bf16 pairs)
  float* as1  = (float*)take((size_t)NN * 8 * 4);
  float* ad1  = (float*)take((size_t)NN * 8 * 4);
  u32*   aggb = (u32*)take((size_t)NN * 128 * 4);     // 25.6MB (bf16 pairs)
  float* den1 = (float*)take((size_t)NN * 8 * 4);     // 1.6MB
  u32*   xs2b = (u32*)take((size_t)NN * 16 * 4);      // 3.2MB
  float* as2  = (float*)take((size_t)NN * 4);
  float* ad2  = (float*)take((size_t)NN * 4);
  float* h2   = (float*)take((size_t)NN * HID * 4);   // fp32
  float* v1s  = (float*)take(256 * 4);
  float* v1d  = (float*)take(256 * 4);
  float* v2s  = (float*)take(256 * 4);
  float* v2d  = (float*)take(256 * 4);

  const int* esrc = ei;
  const int* edst = ei + NE;

  hipMemsetAsync(cnt, 0, (size_t)NN * 4, stream);
  k_vprep<<<1, 256, 0, stream>>>(w1s, w1d, a1s, a1d, w2s, w2d, a2s, a2d,
                                 v1s, v1d, v2s, v2d);
  k_fill<<<(NE + 255) / 256, 256, 0, stream>>>(esrc, edst, cnt, csr);
  k_l1<<<(NN + 31) / 32, 256, 0, stream>>>(x, lin_w, lin_b, v1s, v1d,
                                           h0b, as1, ad1);
  k_aggE<<<NN / 4, 256, 0, stream>>>(cnt, csr, h0b, as1, ad1, aggb, den1);
  k_p12<<<(NN + NB - 1) / NB, 256, 0, stream>>>(aggb, den1, w1s, b1, w2s,
                                                v2s, v2d, xs2b, as2, ad2);
  k_agg2<<<(NN + 7) / 8, 256, 0, stream>>>(cnt, csr, xs2b, as2, ad2, b2, h2);
  k_pred<<<(NL * 8 + 255) / 256, 256, 0, stream>>>(eli, h2, out);
}